// Round 1
// baseline (80.169 us; speedup 1.0000x reference)
//
#include <hip/hip_runtime.h>

// Problem constants (from reference setup_inputs)
constexpr int Bn = 16;
constexpr int Hn = 512;
constexpr int Wn = 512;
constexpr int PADR = 15;              // 31x31 window, pad 15
constexpr float INV_KK = 1.0f / (31.0f * 31.0f);
constexpr int HCHUNK = 64;            // rows per block in fused kernel

// ---------------- init: zero the per-batch accumulators -------------------
__global__ void init_acc_kernel(float* __restrict__ acc) {
    int i = threadIdx.x;
    if (i < 4 * Bn) acc[i] = 0.0f;
}

// ---------------- horizontal 31-tap box sum of mask_f ---------------------
// one block per (b,h) row; 256 threads, 2 px/thread; row staged in LDS
__global__ void hbox_kernel(const int* __restrict__ mask, float* __restrict__ hsum) {
    const int row = blockIdx.x;                 // [0, B*H)
    const int* mrow = mask + (size_t)row * Wn;
    float* orow = hsum + (size_t)row * Wn;
    __shared__ float s[Wn];
    const int t = threadIdx.x;
    for (int i = t; i < Wn; i += 256) {
        int m = mrow[i];
        if (m == 255) m = 0;                    // remap ignore index
        s[i] = (float)m;
    }
    __syncthreads();
    for (int i = t; i < Wn; i += 256) {
        const int lo = (i - PADR < 0) ? 0 : i - PADR;
        const int hi = (i + PADR > Wn - 1) ? Wn - 1 : i + PADR;
        float sum = 0.0f;
        for (int j = lo; j <= hi; ++j) sum += s[j];
        orow[i] = sum;                          // zero padding outside -> just clip
    }
}

// ---- vertical box (sliding window) + full loss math + block reduction ----
// grid: (2 wtiles of 256 cols, 8 hchunks of 64 rows, 16 batches); 256 thr
__global__ void fused_kernel(const float* __restrict__ pred,
                             const int* __restrict__ mask,
                             const float* __restrict__ hsum,
                             float* __restrict__ acc) {
    const int w = blockIdx.x * 256 + threadIdx.x;       // 0..511
    const int h0 = blockIdx.y * HCHUNK;
    const int b = blockIdx.z;

    const float* hs = hsum + (size_t)b * Hn * Wn;
    const int* mk = mask + (size_t)b * Hn * Wn;
    const float* p0b = pred + (size_t)b * 2 * Hn * Wn;
    const float* p1b = p0b + (size_t)Hn * Wn;

    // build initial vertical window sum for h = h0: rows [h0-15, h0+15]
    float vs = 0.0f;
#pragma unroll
    for (int dh = -PADR; dh <= PADR; ++dh) {
        const int hh = h0 + dh;
        if (hh >= 0 && hh < Hn) vs += hs[hh * Wn + w];
    }

    float a_weit = 0.0f, a_wbce = 0.0f, a_inter = 0.0f, a_card = 0.0f;

    for (int h = h0; h < h0 + HCHUNK; ++h) {
        int m = mk[h * Wn + w];
        if (m == 255) m = 0;
        const float mf = (float)m;
        const float p0 = p0b[h * Wn + w];
        const float p1 = p1b[h * Wn + w];

        // stable 2-class log-softmax
        const float mx = fmaxf(p0, p1);
        const float lse = mx + __logf(__expf(p0 - mx) + __expf(p1 - mx));
        const float lp0 = p0 - lse;
        const float lp1 = p1 - lse;

        const float wbce = m ? -lp1 : -lp0;
        const float p1s = __expf(lp1);          // softmax prob of class 1

        const float pooled = vs * INV_KK;
        const float weit = 1.0f + 5.0f * fabsf(pooled - mf);

        a_weit += weit;
        a_wbce += weit * wbce;
        a_inter += p1s * mf * weit;
        a_card += (p1s + mf) * weit;

        // slide window down one row: next window [h-14, h+16]
        const int hadd = h + 1 + PADR;
        const int hsub = h - PADR;
        if (hadd < Hn) vs += hs[hadd * Wn + w];
        if (hsub >= 0) vs -= hs[hsub * Wn + w];
    }

    // block reduction: 4 waves of 64
    const int lane = threadIdx.x & 63;
    const int wv = threadIdx.x >> 6;
    __shared__ float red[4][4];
#pragma unroll
    for (int off = 32; off > 0; off >>= 1) {
        a_weit += __shfl_down(a_weit, off, 64);
        a_wbce += __shfl_down(a_wbce, off, 64);
        a_inter += __shfl_down(a_inter, off, 64);
        a_card += __shfl_down(a_card, off, 64);
    }
    if (lane == 0) {
        red[wv][0] = a_weit;
        red[wv][1] = a_wbce;
        red[wv][2] = a_inter;
        red[wv][3] = a_card;
    }
    __syncthreads();
    if (threadIdx.x < 4) {
        const float v = red[0][threadIdx.x] + red[1][threadIdx.x] +
                        red[2][threadIdx.x] + red[3][threadIdx.x];
        atomicAdd(&acc[b * 4 + threadIdx.x], v);
    }
}

// ---------------- finalize: per-batch loss, mean over batch ---------------
__global__ void finalize_kernel(const float* __restrict__ acc, float* __restrict__ out) {
    const int t = threadIdx.x;
    float v = 0.0f;
    if (t < Bn) {
        const float sw = acc[t * 4 + 0];
        const float swb = acc[t * 4 + 1];
        const float inter = acc[t * 4 + 2];
        const float card = acc[t * 4 + 3];
        const float wbce = swb / sw;
        const float uni = card - inter;
        const float wiou = 1.0f - (inter + 1.0f) / (uni + 1.0f);
        v = wbce + wiou;
    }
#pragma unroll
    for (int off = 32; off > 0; off >>= 1) v += __shfl_down(v, off, 64);
    if (t == 0) out[0] = v * (1.0f / (float)Bn);
}

extern "C" void kernel_launch(void* const* d_in, const int* in_sizes, int n_in,
                              void* d_out, int out_size, void* d_ws, size_t ws_size,
                              hipStream_t stream) {
    const float* pred = (const float*)d_in[0];
    const int* mask = (const int*)d_in[1];
    float* hsum = (float*)d_ws;                          // B*H*W floats = 16 MB
    float* acc = hsum + (size_t)Bn * Hn * Wn;            // 4*B floats
    float* out = (float*)d_out;

    hipLaunchKernelGGL(init_acc_kernel, dim3(1), dim3(64), 0, stream, acc);
    hipLaunchKernelGGL(hbox_kernel, dim3(Bn * Hn), dim3(256), 0, stream, mask, hsum);
    hipLaunchKernelGGL(fused_kernel, dim3(2, 8, Bn), dim3(256), 0, stream,
                       pred, mask, hsum, acc);
    hipLaunchKernelGGL(finalize_kernel, dim3(1), dim3(64), 0, stream, acc, out);
}

// Round 2
// 51.905 us; speedup vs baseline: 1.5445x; 1.5445x over previous
//
#include <hip/hip_runtime.h>

// Problem constants (from reference setup_inputs)
constexpr int Bn = 16;
constexpr int Hn = 512;
constexpr int Wn = 512;
constexpr int PADR = 15;              // 31x31 window, pad 15
constexpr float INV_KK = 1.0f / (31.0f * 31.0f);
constexpr int HCHUNK = 8;             // rows per block in fused kernel -> 2048 blocks

// ---------------- init: zero the per-batch accumulators -------------------
__global__ void init_acc_kernel(float* __restrict__ acc) {
    int i = threadIdx.x;
    if (i < 4 * Bn) acc[i] = 0.0f;
}

// ---------------- horizontal 31-tap box sum of mask_f ---------------------
// one block per (b,h) row; 256 threads. Prefix-scan formulation:
// hsum[i] = P[min(i+15,511)] - (i>=16 ? P[i-16] : 0), P = inclusive prefix.
__global__ void hbox_kernel(const int* __restrict__ mask, float* __restrict__ hsum) {
    const int row = blockIdx.x;                 // [0, B*H)
    const int* mrow = mask + (size_t)row * Wn;
    float* orow = hsum + (size_t)row * Wn;

    __shared__ float P[Wn];                     // inclusive prefix of the row
    __shared__ float wtot[4];                   // per-wave totals

    const int t = threadIdx.x;
    const int lane = t & 63;
    const int wv = t >> 6;

    // each thread owns elements 2t, 2t+1
    const int2 mm = *reinterpret_cast<const int2*>(mrow + 2 * t);
    const float m0 = (mm.x == 255) ? 0.0f : (float)mm.x;
    const float m1 = (mm.y == 255) ? 0.0f : (float)mm.y;
    float x = m0 + m1;                          // pair sum
    const float pairSum = x;

    // inclusive wave scan over 64 lanes
#pragma unroll
    for (int off = 1; off < 64; off <<= 1) {
        const float n = __shfl_up(x, off, 64);
        if (lane >= off) x += n;
    }
    if (lane == 63) wtot[wv] = x;
    __syncthreads();
    float woff = 0.0f;
#pragma unroll
    for (int k = 0; k < 4; ++k) woff += (k < wv) ? wtot[k] : 0.0f;

    const float pre = woff + (x - pairSum);     // exclusive prefix of pairs
    P[2 * t] = pre + m0;
    P[2 * t + 1] = pre + m0 + m1;
    __syncthreads();

#pragma unroll
    for (int k = 0; k < 2; ++k) {
        const int i = t + k * 256;
        const int hi = (i + PADR > Wn - 1) ? Wn - 1 : i + PADR;
        const float lo = (i >= PADR + 1) ? P[i - PADR - 1] : 0.0f;
        orow[i] = P[hi] - lo;
    }
}

// ---- vertical box (sliding window) + full loss math + block reduction ----
// grid: (2 wtiles of 256 cols, 64 hchunks of 8 rows, 16 batches); 256 thr
__global__ void fused_kernel(const float* __restrict__ pred,
                             const int* __restrict__ mask,
                             const float* __restrict__ hsum,
                             float* __restrict__ acc) {
    const int w = blockIdx.x * 256 + threadIdx.x;       // 0..511
    const int h0 = blockIdx.y * HCHUNK;
    const int b = blockIdx.z;

    const float* hs = hsum + (size_t)b * Hn * Wn;
    const int* mk = mask + (size_t)b * Hn * Wn;
    const float* p0b = pred + (size_t)b * 2 * Hn * Wn;
    const float* p1b = p0b + (size_t)Hn * Wn;

    // build initial vertical window sum for h = h0: rows [h0-15, h0+15]
    float vs = 0.0f;
#pragma unroll
    for (int dh = -PADR; dh <= PADR; ++dh) {
        const int hh = h0 + dh;
        if (hh >= 0 && hh < Hn) vs += hs[hh * Wn + w];
    }

    float a_weit = 0.0f, a_wbce = 0.0f, a_inter = 0.0f, a_card = 0.0f;

#pragma unroll
    for (int h = h0; h < h0 + HCHUNK; ++h) {
        int m = mk[h * Wn + w];
        if (m == 255) m = 0;
        const float mf = (float)m;
        const float p0 = p0b[h * Wn + w];
        const float p1 = p1b[h * Wn + w];

        // stable 2-class log-softmax
        const float mx = fmaxf(p0, p1);
        const float lse = mx + __logf(__expf(p0 - mx) + __expf(p1 - mx));
        const float lp0 = p0 - lse;
        const float lp1 = p1 - lse;

        const float wbce = m ? -lp1 : -lp0;
        const float p1s = __expf(lp1);          // softmax prob of class 1

        const float pooled = vs * INV_KK;
        const float weit = 1.0f + 5.0f * fabsf(pooled - mf);

        a_weit += weit;
        a_wbce += weit * wbce;
        a_inter += p1s * mf * weit;
        a_card += (p1s + mf) * weit;

        // slide window down one row: next window [h-14, h+16]
        const int hadd = h + 1 + PADR;
        const int hsub = h - PADR;
        if (hadd < Hn) vs += hs[hadd * Wn + w];
        if (hsub >= 0) vs -= hs[hsub * Wn + w];
    }

    // block reduction: 4 waves of 64
    const int lane = threadIdx.x & 63;
    const int wv = threadIdx.x >> 6;
    __shared__ float red[4][4];
#pragma unroll
    for (int off = 32; off > 0; off >>= 1) {
        a_weit += __shfl_down(a_weit, off, 64);
        a_wbce += __shfl_down(a_wbce, off, 64);
        a_inter += __shfl_down(a_inter, off, 64);
        a_card += __shfl_down(a_card, off, 64);
    }
    if (lane == 0) {
        red[wv][0] = a_weit;
        red[wv][1] = a_wbce;
        red[wv][2] = a_inter;
        red[wv][3] = a_card;
    }
    __syncthreads();
    if (threadIdx.x < 4) {
        const float v = red[0][threadIdx.x] + red[1][threadIdx.x] +
                        red[2][threadIdx.x] + red[3][threadIdx.x];
        atomicAdd(&acc[b * 4 + threadIdx.x], v);
    }
}

// ---------------- finalize: per-batch loss, mean over batch ---------------
__global__ void finalize_kernel(const float* __restrict__ acc, float* __restrict__ out) {
    const int t = threadIdx.x;
    float v = 0.0f;
    if (t < Bn) {
        const float sw = acc[t * 4 + 0];
        const float swb = acc[t * 4 + 1];
        const float inter = acc[t * 4 + 2];
        const float card = acc[t * 4 + 3];
        const float wbce = swb / sw;
        const float uni = card - inter;
        const float wiou = 1.0f - (inter + 1.0f) / (uni + 1.0f);
        v = wbce + wiou;
    }
#pragma unroll
    for (int off = 32; off > 0; off >>= 1) v += __shfl_down(v, off, 64);
    if (t == 0) out[0] = v * (1.0f / (float)Bn);
}

extern "C" void kernel_launch(void* const* d_in, const int* in_sizes, int n_in,
                              void* d_out, int out_size, void* d_ws, size_t ws_size,
                              hipStream_t stream) {
    const float* pred = (const float*)d_in[0];
    const int* mask = (const int*)d_in[1];
    float* hsum = (float*)d_ws;                          // B*H*W floats = 16 MB
    float* acc = hsum + (size_t)Bn * Hn * Wn;            // 4*B floats
    float* out = (float*)d_out;

    hipLaunchKernelGGL(init_acc_kernel, dim3(1), dim3(64), 0, stream, acc);
    hipLaunchKernelGGL(hbox_kernel, dim3(Bn * Hn), dim3(256), 0, stream, mask, hsum);
    hipLaunchKernelGGL(fused_kernel, dim3(2, Hn / HCHUNK, Bn), dim3(256), 0, stream,
                       pred, mask, hsum, acc);
    hipLaunchKernelGGL(finalize_kernel, dim3(1), dim3(64), 0, stream, acc, out);
}